// Round 16
// baseline (548.967 us; speedup 1.0000x reference)
//
#include <hip/hip_runtime.h>
#include <math.h>

#define N_NODES 16384
#define N_EDGES 262144
#define HDIM    128
#define NG50    50
#define NLAYER  6
#define NGRAPH  16
#define TROWS   1025
#define RMAXF   4.34f

__device__ __forceinline__ float ssp_f(float x){
  return (x > 20.0f ? x : log1pf(__expf(x))) - 0.6931471805599453f;
}
__device__ __forceinline__ void fma4(float4& c, float a, const float4 b){
  c.x = fmaf(a,b.x,c.x); c.y = fmaf(a,b.y,c.y); c.z = fmaf(a,b.z,c.z); c.w = fmaf(a,b.w,c.w);
}
// bf16 helpers (RNE)
__device__ __forceinline__ unsigned short f2bf(float x){
  unsigned u = __float_as_uint(x);
  u += 0x7FFF + ((u>>16)&1);
  return (unsigned short)(u>>16);
}
__device__ __forceinline__ float bf2f(unsigned short u){
  return __uint_as_float(((unsigned)u)<<16);
}
// plain cooperative chunk load (k_gemm_xh)
__device__ __forceinline__ void load_chunk(float* Bs, const float* W, int kc, int tid){
  const float4* src = (const float4*)(W + kc*HDIM);
  float4* dst = (float4*)Bs;
  #pragma unroll
  for (int i=0;i<4;++i) dst[tid + i*256] = src[tid + i*256];
}
// async global->LDS DMA staging of one 32x128 fp32 chunk (16 KB). Zero VGPR
// temporaries -> immune to the R8/R10 scratch-spill. (R15: verified, no spill.)
typedef const __attribute__((address_space(1))) unsigned int* gp_t;
typedef __attribute__((address_space(3))) unsigned int* lp_t;
__device__ __forceinline__ void stage_dma(float* BsDst, const float* W, int kc, int tid){
  const float4* g = (const float4*)(W + kc*HDIM);
  float4* l = (float4*)BsDst;
  int lane  = tid & 63;
  int wbase = tid & 192;
  #pragma unroll
  for (int i=0;i<4;++i){
    int base = i*256 + wbase;
    __builtin_amdgcn_global_load_lds((gp_t)(const void*)(g + base + lane),
                                     (lp_t)(void*)(l + base), 16, 0, 0);
  }
}

// ---------------- h = emb[z] ----------------
__global__ __launch_bounds__(256) void k_init_h(const int* __restrict__ z,
    const float* __restrict__ emb, float* __restrict__ h){
  int t = blockIdx.x*256 + threadIdx.x;
  int n = t >> 5, q = t & 31;
  ((float4*)h)[t] = ((const float4*)emb)[(z[n]<<5) + q];
}

// ---------------- per-layer filter tables: 4 rows/block, split-k ----------------
#define TAB_R  4
#define TAB_NB 257   // ceil(1025/4)
__global__ __launch_bounds__(256) void k_tab(const float* __restrict__ w1, const float* __restrict__ b1,
      const float* __restrict__ w2, const float* __restrict__ b2, float* __restrict__ tab){
  __shared__ float ea[TAB_R][52];
  __shared__ float sT[TAB_R][HDIM];
  __shared__ float part[2][TAB_R][HDIM];
  int l  = blockIdx.x / TAB_NB;
  int i0 = (blockIdx.x % TAB_NB) * TAB_R;
  int tid = threadIdx.x;
  int j    = tid & 127;
  int half = tid >> 7;
  const float* w1l = w1 + (size_t)l*NG50*HDIM;
  const float* w2l = w2 + (size_t)l*HDIM*HDIM;
  float* tabl = tab + (size_t)l*TROWS*HDIM;
  const float STEP = RMAXF/1024.0f;
  const float GS   = 10.0f/49.0f;
  const float GC   = -0.5f/(GS*GS);
  if (tid < TAB_R*NG50){
    int rr = tid / NG50, k = tid - rr*NG50;
    int ri = i0 + rr; if (ri > TROWS-1) ri = TROWS-1;
    float d = ri*STEP - k*GS;
    ea[rr][k] = __expf(GC*d*d);
  }
  __syncthreads();
  {
    float acc[TAB_R] = {0,0,0,0};
    int kb = half*25;
    for (int k=0;k<25;++k){
      float wv = w1l[(kb+k)*HDIM + j];
      #pragma unroll
      for (int r=0;r<TAB_R;++r) acc[r] = fmaf(ea[r][kb+k], wv, acc[r]);
    }
    #pragma unroll
    for (int r=0;r<TAB_R;++r) part[half][r][j] = acc[r];
  }
  __syncthreads();
  {
    float b1v = b1[(size_t)l*HDIM + j];
    #pragma unroll
    for (int rr=0;rr<2;++rr){
      int r = half*2 + rr;
      sT[r][j] = ssp_f(part[0][r][j] + part[1][r][j] + b1v);
    }
  }
  __syncthreads();
  {
    float o[TAB_R] = {0,0,0,0};
    int kb = half*64;
    #pragma unroll 4
    for (int k=0;k<64;++k){
      float wv = w2l[(kb+k)*HDIM + j];
      #pragma unroll
      for (int r=0;r<TAB_R;++r) o[r] = fmaf(sT[r][kb+k], wv, o[r]);
    }
    #pragma unroll
    for (int r=0;r<TAB_R;++r) part[half][r][j] = o[r];
  }
  __syncthreads();
  {
    float b2v = b2[(size_t)l*HDIM + j];
    #pragma unroll
    for (int rr=0;rr<2;++rr){
      int r = half*2 + rr;
      int ri = i0 + r;
      if (ri < TROWS){
        float rv = ri*STEP;
        float C = 0.5f*(cosf(rv*0.31415926535897931f) + 1.0f);
        tabl[(size_t)ri*HDIM + j] = (part[0][r][j] + part[1][r][j] + b2v)*C;
      }
    }
  }
}

// ---------------- pack lerp pairs as bf16, channel-split layout ----------------
// tabp2[l][p][i][lane] = {tab[i][p*64+lane], tab[i+1][p*64+lane]}   (ushort2)
__global__ __launch_bounds__(256) void k_pack(const float* __restrict__ tab, ushort2* __restrict__ tabp2){
  size_t t = (size_t)blockIdx.x*256 + threadIdx.x;   // over 6*2*1024*64
  int lane = (int)(t & 63);
  size_t i = (t >> 6) & 1023;
  size_t p = (t >> 16) & 1;
  size_t l = t >> 17;
  int ch = (int)(p*64) + lane;
  const float* a = tab + (l*TROWS + i)*HDIM + ch;
  ushort2 o;
  o.x = f2bf(a[0]);
  o.y = f2bf(a[HDIM]);
  tabp2[t] = o;
}

// ---------------- CSR build ----------------
__global__ __launch_bounds__(256) void k_hist(const int* __restrict__ ei, int* __restrict__ cursor){
  int e = blockIdx.x*256 + threadIdx.x;
  if (e < N_EDGES) atomicAdd(&cursor[ei[N_EDGES + e]], 1);
}
__global__ __launch_bounds__(1024) void k_scan(int* __restrict__ cursor, int* __restrict__ rowptr){
  __shared__ int sbuf[1024];
  int t = threadIdx.x;
  int base = t*16;
  int d[16]; int s = 0;
  #pragma unroll
  for (int i=0;i<16;++i){ d[i] = cursor[base+i]; s += d[i]; }
  sbuf[t] = s; __syncthreads();
  for (int off=1; off<1024; off<<=1){
    int v = sbuf[t];
    int add = (t >= off) ? sbuf[t-off] : 0;
    __syncthreads();
    sbuf[t] = v + add;
    __syncthreads();
  }
  int run = (t==0) ? 0 : sbuf[t-1];
  #pragma unroll
  for (int i=0;i<16;++i){ rowptr[base+i] = run; cursor[base+i] = run; run += d[i]; }
  if (t==1023) rowptr[N_NODES] = run;
}
__global__ __launch_bounds__(256) void k_fill(const int* __restrict__ ei, const float* __restrict__ pos,
    int* __restrict__ cursor, int* __restrict__ srcl, float* __restrict__ tl){
  int e = blockIdx.x*256 + threadIdx.x;
  if (e < N_EDGES){
    int a = ei[e];
    int c = ei[N_EDGES + e];
    float dx = pos[3*a+0] - pos[3*c+0];
    float dy = pos[3*a+1] - pos[3*c+1];
    float dz = pos[3*a+2] - pos[3*c+2];
    dx -= rintf(dx*0.2f)*5.0f;
    dy -= rintf(dy*0.2f)*5.0f;
    dz -= rintf(dz*0.2f)*5.0f;
    float r = sqrtf(fmaf(dx,dx,fmaf(dy,dy,dz*dz)));
    int slot = atomicAdd(&cursor[c], 1);
    srcl[slot] = a;
    tl[slot]   = r * (1024.0f/RMAXF);
  }
}

// write 4 bf16 channels j0..j0+3 of node into the channel-split xhb layout
__device__ __forceinline__ void store_xh4(unsigned short* xhb, int node, int j0, ushort4 o){
  int p = j0 >> 6;
  int off = j0 & 63;
  *(ushort4*)(xhb + (size_t)p*N_NODES*64 + (size_t)node*64 + off) = o;
}

// ---------------- xh(bf16,split) = h @ cf_w1[0] ----------------
#define FR 16
__global__ __launch_bounds__(256,4) void k_gemm_xh(const float* __restrict__ A,
    const float* __restrict__ B, unsigned short* __restrict__ xhb){
  __shared__ float Bs[32*HDIM];
  int tid = threadIdx.x;
  int m0 = blockIdx.x*FR;
  int tc = tid & 31, tr = tid >> 5;
  int j0 = tc*4;
  int lr0 = tr*2, lr1 = tr*2+1;
  float4 acc0 = make_float4(0,0,0,0), acc1 = acc0;
  const float* A0 = A + (size_t)(m0 + lr0)*HDIM;
  const float* A1 = A + (size_t)(m0 + lr1)*HDIM;
  for (int kc=0; kc<HDIM; kc+=32){
    __syncthreads();
    load_chunk(Bs, B, kc, tid);
    __syncthreads();
    #pragma unroll
    for (int kk=0; kk<32; kk+=4){
      float4 b0 = *(const float4*)(Bs + (kk+0)*HDIM + j0);
      float4 b1 = *(const float4*)(Bs + (kk+1)*HDIM + j0);
      float4 b2 = *(const float4*)(Bs + (kk+2)*HDIM + j0);
      float4 b3 = *(const float4*)(Bs + (kk+3)*HDIM + j0);
      float4 a0 = *(const float4*)(A0 + kc + kk);
      float4 a1 = *(const float4*)(A1 + kc + kk);
      fma4(acc0,a0.x,b0); fma4(acc0,a0.y,b1); fma4(acc0,a0.z,b2); fma4(acc0,a0.w,b3);
      fma4(acc1,a1.x,b0); fma4(acc1,a1.y,b1); fma4(acc1,a1.z,b2); fma4(acc1,a1.w,b3);
    }
  }
  ushort4 o;
  o.x=f2bf(acc0.x); o.y=f2bf(acc0.y); o.z=f2bf(acc0.z); o.w=f2bf(acc0.w);
  store_xh4(xhb, m0 + lr0, j0, o);
  o.x=f2bf(acc1.x); o.y=f2bf(acc1.y); o.z=f2bf(acc1.z); o.w=f2bf(acc1.w);
  store_xh4(xhb, m0 + lr1, j0, o);
}

// ---------------- edge aggregation: two channel-split passes for L2 residency ----------------
// grid 8192: blocks [0,4096) do channels 0-63, [4096,8192) do 64-127.
// Per-pass working set = 2 MB xh-half + 256 KB table-half < 4 MB per-XCD L2.
// Per-channel accumulation order identical to before -> bit-identical output.
__global__ __launch_bounds__(256) void k_agg(const int* __restrict__ rowptr,
    const int* __restrict__ srcl, const float* __restrict__ tl,
    const ushort2* __restrict__ tabp2, const unsigned short* __restrict__ xhb,
    float* __restrict__ agg){
  int bp = blockIdx.x >> 12;                       // pass (channel half)
  int c  = (blockIdx.x & 4095)*4 + (threadIdx.x >> 6);
  int lane = threadIdx.x & 63;
  int beg = rowptr[c], end = rowptr[c+1];
  const ushort2*       tabl = tabp2 + (size_t)bp*1024*64 + lane;
  const unsigned short* xh2 = xhb + (size_t)bp*N_NODES*64 + lane;
  float ax = 0.f;
  for (int k0 = beg; k0 < end; k0 += 64){
    int rem = end - k0;
    int cnt = rem < 64 ? rem : 64;
    int   s_l = 0; float t_l = 0.f;
    if (lane < cnt){ s_l = srcl[k0+lane]; t_l = tl[k0+lane]; }
    int j = 0;
    for (; j+3 < cnt; j += 4){
      int   r0 = __shfl(s_l, j,   64);
      float t0 = __shfl(t_l, j,   64);
      int   r1 = __shfl(s_l, j+1, 64);
      float t1 = __shfl(t_l, j+1, 64);
      int   r2 = __shfl(s_l, j+2, 64);
      float t2 = __shfl(t_l, j+2, 64);
      int   r3 = __shfl(s_l, j+3, 64);
      float t3 = __shfl(t_l, j+3, 64);
      int i00 = (int)t0; if (i00 > 1023) i00 = 1023;
      int i01 = (int)t1; if (i01 > 1023) i01 = 1023;
      int i02 = (int)t2; if (i02 > 1023) i02 = 1023;
      int i03 = (int)t3; if (i03 > 1023) i03 = 1023;
      float f0 = t0 - (float)i00;
      float f1 = t1 - (float)i01;
      float f2 = t2 - (float)i02;
      float f3 = t3 - (float)i03;
      ushort2 p0 = tabl[(size_t)i00*64];
      ushort2 p1 = tabl[(size_t)i01*64];
      ushort2 p2 = tabl[(size_t)i02*64];
      ushort2 p3 = tabl[(size_t)i03*64];
      unsigned short x0 = xh2[(size_t)r0*64];
      unsigned short x1 = xh2[(size_t)r1*64];
      unsigned short x2 = xh2[(size_t)r2*64];
      unsigned short x3 = xh2[(size_t)r3*64];
      float a0 = bf2f(p0.x), d0 = bf2f(p0.y)-a0;
      float a1 = bf2f(p1.x), d1 = bf2f(p1.y)-a1;
      float a2 = bf2f(p2.x), d2 = bf2f(p2.y)-a2;
      float a3 = bf2f(p3.x), d3 = bf2f(p3.y)-a3;
      ax = fmaf(bf2f(x0), fmaf(f0, d0, a0), ax);
      ax = fmaf(bf2f(x1), fmaf(f1, d1, a1), ax);
      ax = fmaf(bf2f(x2), fmaf(f2, d2, a2), ax);
      ax = fmaf(bf2f(x3), fmaf(f3, d3, a3), ax);
    }
    for (; j < cnt; ++j){
      int   r0 = __shfl(s_l, j, 64);
      float t0 = __shfl(t_l, j, 64);
      int i00 = (int)t0; if (i00 > 1023) i00 = 1023;
      float f0 = t0 - (float)i00;
      ushort2 p0 = tabl[(size_t)i00*64];
      unsigned short x0 = xh2[(size_t)r0*64];
      float a0 = bf2f(p0.x), d0 = bf2f(p0.y)-a0;
      ax = fmaf(bf2f(x0), fmaf(f0, d0, a0), ax);
    }
  }
  agg[(size_t)c*HDIM + bp*64 + lane] = ax;
}

// ---------------- fused interaction: DMA double-buffered weight chunks (R15) ----------------
#define FMA_BLOCK(BSP, AROW0, AROW1)                                   \
  _Pragma("unroll")                                                    \
  for (int kk=0; kk<32; kk+=4){                                        \
    float4 b0 = *(const float4*)((BSP) + (kk+0)*HDIM + j0);            \
    float4 b1 = *(const float4*)((BSP) + (kk+1)*HDIM + j0);            \
    float4 b2 = *(const float4*)((BSP) + (kk+2)*HDIM + j0);            \
    float4 b3 = *(const float4*)((BSP) + (kk+3)*HDIM + j0);            \
    float4 a0 = *(const float4*)((AROW0) + kk);                        \
    float4 a1 = *(const float4*)((AROW1) + kk);                        \
    fma4(acc0,a0.x,b0); fma4(acc0,a0.y,b1); fma4(acc0,a0.z,b2); fma4(acc0,a0.w,b3); \
    fma4(acc1,a1.x,b0); fma4(acc1,a1.y,b1); fma4(acc1,a1.z,b2); fma4(acc1,a1.w,b3); \
  }
template<bool LAST>
__global__ __launch_bounds__(256,4) void k_fused3(const float* __restrict__ Ain,
    const float* __restrict__ W2, const float* __restrict__ B2,
    const float* __restrict__ WL, const float* __restrict__ BL,
    float* __restrict__ Hio, const float* __restrict__ W1n, unsigned short* __restrict__ xhb){
  __shared__ float BsA[32*HDIM];
  __shared__ float BsB[32*HDIM];
  __shared__ float Ss[FR*HDIM];
  int tid = threadIdx.x;
  int m0 = blockIdx.x*FR;
  int tc = tid & 31, tr = tid >> 5;
  int j0 = tc*4;
  int lr0 = tr*2, lr1 = tr*2+1;
  float4 acc0, acc1;
  float* Bcur = BsA;
  float* Bnxt = BsB;

  stage_dma(Bcur, W2, 0, tid);
  __syncthreads();

  // ---- stage A ----
  acc0 = make_float4(0,0,0,0); acc1 = acc0;
  {
    const float* A0 = Ain + (size_t)(m0 + lr0)*HDIM;
    const float* A1 = Ain + (size_t)(m0 + lr1)*HDIM;
    for (int kc=0; kc<HDIM; kc+=32){
      if (kc+32 < HDIM) stage_dma(Bnxt, W2, kc+32, tid);
      else              stage_dma(Bnxt, WL, 0, tid);
      FMA_BLOCK(Bcur, A0 + kc, A1 + kc);
      __syncthreads();
      float* tmp = Bcur; Bcur = Bnxt; Bnxt = tmp;
    }
  }
  {
    float4 b2v = *(const float4*)(B2 + j0);
    float4 v;
    v.x=ssp_f(acc0.x+b2v.x); v.y=ssp_f(acc0.y+b2v.y); v.z=ssp_f(acc0.z+b2v.z); v.w=ssp_f(acc0.w+b2v.w);
    *(float4*)(Ss + lr0*HDIM + j0) = v;
    v.x=ssp_f(acc1.x+b2v.x); v.y=ssp_f(acc1.y+b2v.y); v.z=ssp_f(acc1.z+b2v.z); v.w=ssp_f(acc1.w+b2v.w);
    *(float4*)(Ss + lr1*HDIM + j0) = v;
  }
  __syncthreads();

  // ---- stage B ----
  acc0 = make_float4(0,0,0,0); acc1 = acc0;
  for (int kc=0; kc<HDIM; kc+=32){
    if (kc+32 < HDIM)   stage_dma(Bnxt, WL, kc+32, tid);
    else if (!LAST)     stage_dma(Bnxt, W1n, 0, tid);
    FMA_BLOCK(Bcur, Ss + lr0*HDIM + kc, Ss + lr1*HDIM + kc);
    __syncthreads();
    float* tmp = Bcur; Bcur = Bnxt; Bnxt = tmp;
  }
  {
    float4 blv = *(const float4*)(BL + j0);
    float* H0 = Hio + (size_t)(m0 + lr0)*HDIM + j0;
    float* H1 = Hio + (size_t)(m0 + lr1)*HDIM + j0;
    float4 hv;
    hv = *(float4*)H0;
    hv.x += acc0.x+blv.x; hv.y += acc0.y+blv.y; hv.z += acc0.z+blv.z; hv.w += acc0.w+blv.w;
    *(float4*)H0 = hv; if (!LAST) *(float4*)(Ss + lr0*HDIM + j0) = hv;
    hv = *(float4*)H1;
    hv.x += acc1.x+blv.x; hv.y += acc1.y+blv.y; hv.z += acc1.z+blv.z; hv.w += acc1.w+blv.w;
    *(float4*)H1 = hv; if (!LAST) *(float4*)(Ss + lr1*HDIM + j0) = hv;
  }
  if (LAST) return;
  __syncthreads();

  // ---- stage C: xh_next(bf16,split) = h' @ W1n ----
  acc0 = make_float4(0,0,0,0); acc1 = acc0;
  for (int kc=0; kc<HDIM; kc+=32){
    if (kc+32 < HDIM) stage_dma(Bnxt, W1n, kc+32, tid);
    FMA_BLOCK(Bcur, Ss + lr0*HDIM + kc, Ss + lr1*HDIM + kc);
    __syncthreads();
    float* tmp = Bcur; Bcur = Bnxt; Bnxt = tmp;
  }
  ushort4 o;
  o.x=f2bf(acc0.x); o.y=f2bf(acc0.y); o.z=f2bf(acc0.z); o.w=f2bf(acc0.w);
  store_xh4(xhb, m0 + lr0, j0, o);
  o.x=f2bf(acc1.x); o.y=f2bf(acc1.y); o.z=f2bf(acc1.z); o.w=f2bf(acc1.w);
  store_xh4(xhb, m0 + lr1, j0, o);
}

// ---------------- output MLP: per-node scalar (no atomics) ----------------
__global__ __launch_bounds__(256) void k_outA(const float* __restrict__ h, const float* __restrict__ w1,
    const float* __restrict__ b1, const float* __restrict__ w2, const float* __restrict__ b2,
    float* __restrict__ nodeval){
  int node = blockIdx.x*4 + (threadIdx.x >> 6);
  int lane = threadIdx.x & 63;
  float acc = b1[lane];
  const float* hrow = h + (size_t)node*HDIM;
  #pragma unroll 4
  for (int k=0;k<HDIM;++k) acc = fmaf(hrow[k], w1[k*64 + lane], acc);
  float s = ssp_f(acc) * w2[lane];
  for (int off=32; off>0; off>>=1) s += __shfl_down(s, off, 64);
  if (lane == 0) nodeval[node] = s + b2[0];
}

// ---------------- graph readout ----------------
__global__ __launch_bounds__(256) void k_outB(const float* __restrict__ nodeval,
    const int* __restrict__ batch, float* __restrict__ out){
  __shared__ float sred[4];
  int g = blockIdx.x;
  int t = threadIdx.x;
  float s = 0.f;
  for (int n = t; n < N_NODES; n += 256)
    if (batch[n] == g) s += nodeval[n];
  for (int off=32; off>0; off>>=1) s += __shfl_down(s, off, 64);
  if ((t & 63) == 0) sred[t >> 6] = s;
  __syncthreads();
  if (t == 0){
    float tot = sred[0] + sred[1] + sred[2] + sred[3];
    out[g] = 1.0f/(1.0f + __expf(-tot));
  }
}

// ---------------- host ----------------
extern "C" void kernel_launch(void* const* d_in, const int* in_sizes, int n_in,
                              void* d_out, int out_size, void* d_ws, size_t ws_size,
                              hipStream_t stream){
  (void)in_sizes; (void)n_in; (void)out_size;
  const int*   z      = (const int*)  d_in[0];
  const float* pos    = (const float*)d_in[1];
  const int*   ei     = (const int*)  d_in[2];
  const int*   batch  = (const int*)  d_in[3];
  const float* emb    = (const float*)d_in[4];
  const float* mlp_w1 = (const float*)d_in[5];
  const float* mlp_b1 = (const float*)d_in[6];
  const float* mlp_w2 = (const float*)d_in[7];
  const float* mlp_b2 = (const float*)d_in[8];
  const float* cf_w1  = (const float*)d_in[9];
  const float* cf_w2  = (const float*)d_in[10];
  const float* cf_b2  = (const float*)d_in[11];
  const float* lin_w  = (const float*)d_in[12];
  const float* lin_b  = (const float*)d_in[13];
  const float* ow1    = (const float*)d_in[14];
  const float* ob1    = (const float*)d_in[15];
  const float* ow2    = (const float*)d_in[16];
  const float* ob2    = (const float*)d_in[17];

  char* wp = (char*)d_ws;
  size_t used = 0;
  auto alloc = [&](size_t bytes)->char*{
    char* p = wp + used;
    used += (bytes + 1023) & ~(size_t)1023;
    return p;
  };
  float*          tab     = (float*)alloc((size_t)NLAYER*TROWS*HDIM*4);
  ushort2*        tabp2   = (ushort2*)alloc((size_t)NLAYER*2*1024*64*4);
  float*          h       = (float*)alloc((size_t)N_NODES*HDIM*4);
  unsigned short* xhb     = (unsigned short*)alloc((size_t)2*N_NODES*64*2);
  float*          agg     = (float*)alloc((size_t)N_NODES*HDIM*4);
  int*            rowptr  = (int*)  alloc((size_t)(N_NODES+1)*4);
  int*            cursor  = (int*)  alloc((size_t)N_NODES*4);
  int*            srcl    = (int*)  alloc((size_t)N_EDGES*4);
  float*          tl      = (float*)alloc((size_t)N_EDGES*4);
  float*          nodeval = (float*)alloc((size_t)N_NODES*4);
  if (used > ws_size) return;

  hipMemsetAsync(cursor, 0, (size_t)N_NODES*4, stream);

  k_init_h<<<N_NODES*32/256, 256, 0, stream>>>(z, emb, h);
  k_tab   <<<NLAYER*TAB_NB, 256, 0, stream>>>(mlp_w1, mlp_b1, mlp_w2, mlp_b2, tab);
  k_pack  <<<NLAYER*2*1024*64/256, 256, 0, stream>>>(tab, tabp2);
  k_hist  <<<N_EDGES/256, 256, 0, stream>>>(ei, cursor);
  k_scan  <<<1, 1024, 0, stream>>>(cursor, rowptr);
  k_fill  <<<N_EDGES/256, 256, 0, stream>>>(ei, pos, cursor, srcl, tl);

  k_gemm_xh<<<N_NODES/FR, 256, 0, stream>>>(h, cf_w1, xhb);
  for (int l=0; l<NLAYER; ++l){
    k_agg<<<8192, 256, 0, stream>>>(rowptr, srcl, tl,
                 tabp2 + (size_t)l*2*1024*64, xhb, agg);
    if (l < NLAYER-1){
      k_fused3<false><<<N_NODES/FR, 256, 0, stream>>>(agg,
                 cf_w2 + (size_t)l*HDIM*HDIM, cf_b2 + (size_t)l*HDIM,
                 lin_w + (size_t)l*HDIM*HDIM, lin_b + (size_t)l*HDIM, h,
                 cf_w1 + (size_t)(l+1)*HDIM*HDIM, xhb);
    } else {
      k_fused3<true><<<N_NODES/FR, 256, 0, stream>>>(agg,
                 cf_w2 + (size_t)l*HDIM*HDIM, cf_b2 + (size_t)l*HDIM,
                 lin_w + (size_t)l*HDIM*HDIM, lin_b + (size_t)l*HDIM, h,
                 nullptr, nullptr);
    }
  }
  k_outA  <<<N_NODES/4, 256, 0, stream>>>(h, ow1, ob1, ow2, ob2, nodeval);
  k_outB  <<<NGRAPH, 256, 0, stream>>>(nodeval, batch, (float*)d_out);
}

// Round 17
// 514.085 us; speedup vs baseline: 1.0679x; 1.0679x over previous
//
#include <hip/hip_runtime.h>
#include <math.h>

#define N_NODES 16384
#define N_EDGES 262144
#define HDIM    128
#define NG50    50
#define NLAYER  6
#define NGRAPH  16
#define TROWS   1025
#define RMAXF   4.34f

__device__ __forceinline__ float ssp_f(float x){
  return (x > 20.0f ? x : log1pf(__expf(x))) - 0.6931471805599453f;
}
__device__ __forceinline__ void fma4(float4& c, float a, const float4 b){
  c.x = fmaf(a,b.x,c.x); c.y = fmaf(a,b.y,c.y); c.z = fmaf(a,b.z,c.z); c.w = fmaf(a,b.w,c.w);
}
// bf16 helpers (RNE)
__device__ __forceinline__ unsigned short f2bf(float x){
  unsigned u = __float_as_uint(x);
  u += 0x7FFF + ((u>>16)&1);
  return (unsigned short)(u>>16);
}
__device__ __forceinline__ float bf2f(unsigned short u){
  return __uint_as_float(((unsigned)u)<<16);
}
// plain cooperative chunk load (k_gemm_xh)
__device__ __forceinline__ void load_chunk(float* Bs, const float* W, int kc, int tid){
  const float4* src = (const float4*)(W + kc*HDIM);
  float4* dst = (float4*)Bs;
  #pragma unroll
  for (int i=0;i<4;++i) dst[tid + i*256] = src[tid + i*256];
}
// async global->LDS DMA staging of one 32x128 fp32 chunk (16 KB). Zero VGPR
// temporaries -> immune to the R8/R10 scratch-spill. (R15: verified, no spill.)
typedef const __attribute__((address_space(1))) unsigned int* gp_t;
typedef __attribute__((address_space(3))) unsigned int* lp_t;
__device__ __forceinline__ void stage_dma(float* BsDst, const float* W, int kc, int tid){
  const float4* g = (const float4*)(W + kc*HDIM);
  float4* l = (float4*)BsDst;
  int lane  = tid & 63;
  int wbase = tid & 192;
  #pragma unroll
  for (int i=0;i<4;++i){
    int base = i*256 + wbase;
    __builtin_amdgcn_global_load_lds((gp_t)(const void*)(g + base + lane),
                                     (lp_t)(void*)(l + base), 16, 0, 0);
  }
}

// ---------------- h = emb[z] ----------------
__global__ __launch_bounds__(256) void k_init_h(const int* __restrict__ z,
    const float* __restrict__ emb, float* __restrict__ h){
  int t = blockIdx.x*256 + threadIdx.x;
  int n = t >> 5, q = t & 31;
  ((float4*)h)[t] = ((const float4*)emb)[(z[n]<<5) + q];
}

// ---------------- per-layer filter tables: 4 rows/block, split-k ----------------
#define TAB_R  4
#define TAB_NB 257   // ceil(1025/4)
__global__ __launch_bounds__(256) void k_tab(const float* __restrict__ w1, const float* __restrict__ b1,
      const float* __restrict__ w2, const float* __restrict__ b2, float* __restrict__ tab){
  __shared__ float ea[TAB_R][52];
  __shared__ float sT[TAB_R][HDIM];
  __shared__ float part[2][TAB_R][HDIM];
  int l  = blockIdx.x / TAB_NB;
  int i0 = (blockIdx.x % TAB_NB) * TAB_R;
  int tid = threadIdx.x;
  int j    = tid & 127;
  int half = tid >> 7;
  const float* w1l = w1 + (size_t)l*NG50*HDIM;
  const float* w2l = w2 + (size_t)l*HDIM*HDIM;
  float* tabl = tab + (size_t)l*TROWS*HDIM;
  const float STEP = RMAXF/1024.0f;
  const float GS   = 10.0f/49.0f;
  const float GC   = -0.5f/(GS*GS);
  if (tid < TAB_R*NG50){
    int rr = tid / NG50, k = tid - rr*NG50;
    int ri = i0 + rr; if (ri > TROWS-1) ri = TROWS-1;
    float d = ri*STEP - k*GS;
    ea[rr][k] = __expf(GC*d*d);
  }
  __syncthreads();
  {
    float acc[TAB_R] = {0,0,0,0};
    int kb = half*25;
    for (int k=0;k<25;++k){
      float wv = w1l[(kb+k)*HDIM + j];
      #pragma unroll
      for (int r=0;r<TAB_R;++r) acc[r] = fmaf(ea[r][kb+k], wv, acc[r]);
    }
    #pragma unroll
    for (int r=0;r<TAB_R;++r) part[half][r][j] = acc[r];
  }
  __syncthreads();
  {
    float b1v = b1[(size_t)l*HDIM + j];
    #pragma unroll
    for (int rr=0;rr<2;++rr){
      int r = half*2 + rr;
      sT[r][j] = ssp_f(part[0][r][j] + part[1][r][j] + b1v);
    }
  }
  __syncthreads();
  {
    float o[TAB_R] = {0,0,0,0};
    int kb = half*64;
    #pragma unroll 4
    for (int k=0;k<64;++k){
      float wv = w2l[(kb+k)*HDIM + j];
      #pragma unroll
      for (int r=0;r<TAB_R;++r) o[r] = fmaf(sT[r][kb+k], wv, o[r]);
    }
    #pragma unroll
    for (int r=0;r<TAB_R;++r) part[half][r][j] = o[r];
  }
  __syncthreads();
  {
    float b2v = b2[(size_t)l*HDIM + j];
    #pragma unroll
    for (int rr=0;rr<2;++rr){
      int r = half*2 + rr;
      int ri = i0 + r;
      if (ri < TROWS){
        float rv = ri*STEP;
        float C = 0.5f*(cosf(rv*0.31415926535897931f) + 1.0f);
        tabl[(size_t)ri*HDIM + j] = (part[0][r][j] + part[1][r][j] + b2v)*C;
      }
    }
  }
}

// ---------------- pack lerp pairs as bf16 ----------------
__global__ __launch_bounds__(256) void k_pack(const float* __restrict__ tab, ushort4* __restrict__ tabp){
  size_t t = (size_t)blockIdx.x*256 + threadIdx.x;
  int lane = (int)(t & 63);
  size_t row = t >> 6;
  size_t l = row >> 10, i = row & 1023;
  const float* a = tab + (l*TROWS + i)*HDIM + lane*2;
  float2 av = *(const float2*)a;
  float2 bv = *(const float2*)(a + HDIM);
  ushort4 p;
  p.x = f2bf(av.x); p.y = f2bf(av.y); p.z = f2bf(bv.x); p.w = f2bf(bv.y);
  tabp[t] = p;
}

// ---------------- CSR build ----------------
__global__ __launch_bounds__(256) void k_hist(const int* __restrict__ ei, int* __restrict__ cursor){
  int e = blockIdx.x*256 + threadIdx.x;
  if (e < N_EDGES) atomicAdd(&cursor[ei[N_EDGES + e]], 1);
}
__global__ __launch_bounds__(1024) void k_scan(int* __restrict__ cursor, int* __restrict__ rowptr){
  __shared__ int sbuf[1024];
  int t = threadIdx.x;
  int base = t*16;
  int d[16]; int s = 0;
  #pragma unroll
  for (int i=0;i<16;++i){ d[i] = cursor[base+i]; s += d[i]; }
  sbuf[t] = s; __syncthreads();
  for (int off=1; off<1024; off<<=1){
    int v = sbuf[t];
    int add = (t >= off) ? sbuf[t-off] : 0;
    __syncthreads();
    sbuf[t] = v + add;
    __syncthreads();
  }
  int run = (t==0) ? 0 : sbuf[t-1];
  #pragma unroll
  for (int i=0;i<16;++i){ rowptr[base+i] = run; cursor[base+i] = run; run += d[i]; }
  if (t==1023) rowptr[N_NODES] = run;
}
__global__ __launch_bounds__(256) void k_fill(const int* __restrict__ ei, const float* __restrict__ pos,
    int* __restrict__ cursor, int* __restrict__ srcl, float* __restrict__ tl){
  int e = blockIdx.x*256 + threadIdx.x;
  if (e < N_EDGES){
    int a = ei[e];
    int c = ei[N_EDGES + e];
    float dx = pos[3*a+0] - pos[3*c+0];
    float dy = pos[3*a+1] - pos[3*c+1];
    float dz = pos[3*a+2] - pos[3*c+2];
    dx -= rintf(dx*0.2f)*5.0f;
    dy -= rintf(dy*0.2f)*5.0f;
    dz -= rintf(dz*0.2f)*5.0f;
    float r = sqrtf(fmaf(dx,dx,fmaf(dy,dy,dz*dz)));
    int slot = atomicAdd(&cursor[c], 1);
    srcl[slot] = a;
    tl[slot]   = r * (1024.0f/RMAXF);
  }
}

// ---------------- xh(bf16) = h @ cf_w1[0] ----------------
#define FR 16
__global__ __launch_bounds__(256,4) void k_gemm_xh(const float* __restrict__ A,
    const float* __restrict__ B, ushort4* __restrict__ Cb){
  __shared__ float Bs[32*HDIM];
  int tid = threadIdx.x;
  int m0 = blockIdx.x*FR;
  int tc = tid & 31, tr = tid >> 5;
  int j0 = tc*4;
  int lr0 = tr*2, lr1 = tr*2+1;
  float4 acc0 = make_float4(0,0,0,0), acc1 = acc0;
  const float* A0 = A + (size_t)(m0 + lr0)*HDIM;
  const float* A1 = A + (size_t)(m0 + lr1)*HDIM;
  for (int kc=0; kc<HDIM; kc+=32){
    __syncthreads();
    load_chunk(Bs, B, kc, tid);
    __syncthreads();
    #pragma unroll
    for (int kk=0; kk<32; kk+=4){
      float4 b0 = *(const float4*)(Bs + (kk+0)*HDIM + j0);
      float4 b1 = *(const float4*)(Bs + (kk+1)*HDIM + j0);
      float4 b2 = *(const float4*)(Bs + (kk+2)*HDIM + j0);
      float4 b3 = *(const float4*)(Bs + (kk+3)*HDIM + j0);
      float4 a0 = *(const float4*)(A0 + kc + kk);
      float4 a1 = *(const float4*)(A1 + kc + kk);
      fma4(acc0,a0.x,b0); fma4(acc0,a0.y,b1); fma4(acc0,a0.z,b2); fma4(acc0,a0.w,b3);
      fma4(acc1,a1.x,b0); fma4(acc1,a1.y,b1); fma4(acc1,a1.z,b2); fma4(acc1,a1.w,b3);
    }
  }
  ushort4 o;
  o.x=f2bf(acc0.x); o.y=f2bf(acc0.y); o.z=f2bf(acc0.z); o.w=f2bf(acc0.w);
  Cb[(size_t)(m0 + lr0)*32 + tc] = o;
  o.x=f2bf(acc1.x); o.y=f2bf(acc1.y); o.z=f2bf(acc1.z); o.w=f2bf(acc1.w);
  Cb[(size_t)(m0 + lr1)*32 + tc] = o;
}

// ---------------- edge aggregation (R11 optimum: 4-edge unroll, bf16) ----------------
// R13/R16 bracketing: 8-edge unroll and channel-split both regress; this is
// the issue/latency-bound optimum.
__global__ __launch_bounds__(256) void k_agg(const int* __restrict__ rowptr,
    const int* __restrict__ srcl, const float* __restrict__ tl,
    const ushort4* __restrict__ tabp, const ushort2* __restrict__ xhb, float* __restrict__ agg){
  int c = blockIdx.x*4 + (threadIdx.x >> 6);
  int lane = threadIdx.x & 63;
  int beg = rowptr[c], end = rowptr[c+1];
  const ushort4* tabl = tabp + lane;
  const ushort2* xh2  = xhb + lane;
  float ax = 0.f, ay = 0.f;
  for (int k0 = beg; k0 < end; k0 += 64){
    int rem = end - k0;
    int cnt = rem < 64 ? rem : 64;
    int   s_l = 0; float t_l = 0.f;
    if (lane < cnt){ s_l = srcl[k0+lane]; t_l = tl[k0+lane]; }
    int j = 0;
    for (; j+3 < cnt; j += 4){
      int   r0 = __shfl(s_l, j,   64);
      float t0 = __shfl(t_l, j,   64);
      int   r1 = __shfl(s_l, j+1, 64);
      float t1 = __shfl(t_l, j+1, 64);
      int   r2 = __shfl(s_l, j+2, 64);
      float t2 = __shfl(t_l, j+2, 64);
      int   r3 = __shfl(s_l, j+3, 64);
      float t3 = __shfl(t_l, j+3, 64);
      int i00 = (int)t0; if (i00 > 1023) i00 = 1023;
      int i01 = (int)t1; if (i01 > 1023) i01 = 1023;
      int i02 = (int)t2; if (i02 > 1023) i02 = 1023;
      int i03 = (int)t3; if (i03 > 1023) i03 = 1023;
      float f0 = t0 - (float)i00;
      float f1 = t1 - (float)i01;
      float f2 = t2 - (float)i02;
      float f3 = t3 - (float)i03;
      ushort4 p0 = tabl[(size_t)i00*64];
      ushort4 p1 = tabl[(size_t)i01*64];
      ushort4 p2 = tabl[(size_t)i02*64];
      ushort4 p3 = tabl[(size_t)i03*64];
      ushort2 x0 = xh2[(size_t)r0*64];
      ushort2 x1 = xh2[(size_t)r1*64];
      ushort2 x2 = xh2[(size_t)r2*64];
      ushort2 x3 = xh2[(size_t)r3*64];
      float a0x=bf2f(p0.x), a0y=bf2f(p0.y), d0x=bf2f(p0.z)-a0x, d0y=bf2f(p0.w)-a0y;
      float a1x=bf2f(p1.x), a1y=bf2f(p1.y), d1x=bf2f(p1.z)-a1x, d1y=bf2f(p1.w)-a1y;
      float a2x=bf2f(p2.x), a2y=bf2f(p2.y), d2x=bf2f(p2.z)-a2x, d2y=bf2f(p2.w)-a2y;
      float a3x=bf2f(p3.x), a3y=bf2f(p3.y), d3x=bf2f(p3.z)-a3x, d3y=bf2f(p3.w)-a3y;
      ax = fmaf(bf2f(x0.x), fmaf(f0, d0x, a0x), ax);
      ay = fmaf(bf2f(x0.y), fmaf(f0, d0y, a0y), ay);
      ax = fmaf(bf2f(x1.x), fmaf(f1, d1x, a1x), ax);
      ay = fmaf(bf2f(x1.y), fmaf(f1, d1y, a1y), ay);
      ax = fmaf(bf2f(x2.x), fmaf(f2, d2x, a2x), ax);
      ay = fmaf(bf2f(x2.y), fmaf(f2, d2y, a2y), ay);
      ax = fmaf(bf2f(x3.x), fmaf(f3, d3x, a3x), ax);
      ay = fmaf(bf2f(x3.y), fmaf(f3, d3y, a3y), ay);
    }
    for (; j < cnt; ++j){
      int   r0 = __shfl(s_l, j, 64);
      float t0 = __shfl(t_l, j, 64);
      int i00 = (int)t0; if (i00 > 1023) i00 = 1023;
      float f0 = t0 - (float)i00;
      ushort4 p0 = tabl[(size_t)i00*64];
      ushort2 x0 = xh2[(size_t)r0*64];
      float a0x=bf2f(p0.x), a0y=bf2f(p0.y), d0x=bf2f(p0.z)-a0x, d0y=bf2f(p0.w)-a0y;
      ax = fmaf(bf2f(x0.x), fmaf(f0, d0x, a0x), ax);
      ay = fmaf(bf2f(x0.y), fmaf(f0, d0y, a0y), ay);
    }
  }
  ((float2*)(agg + (size_t)c*HDIM))[lane] = make_float2(ax, ay);
}

// ---------------- fused interaction: DMA double-buffered weight chunks ----------------
#define FMA_BLOCK(BSP, AROW0, AROW1)                                   \
  _Pragma("unroll")                                                    \
  for (int kk=0; kk<32; kk+=4){                                        \
    float4 b0 = *(const float4*)((BSP) + (kk+0)*HDIM + j0);            \
    float4 b1 = *(const float4*)((BSP) + (kk+1)*HDIM + j0);            \
    float4 b2 = *(const float4*)((BSP) + (kk+2)*HDIM + j0);            \
    float4 b3 = *(const float4*)((BSP) + (kk+3)*HDIM + j0);            \
    float4 a0 = *(const float4*)((AROW0) + kk);                        \
    float4 a1 = *(const float4*)((AROW1) + kk);                        \
    fma4(acc0,a0.x,b0); fma4(acc0,a0.y,b1); fma4(acc0,a0.z,b2); fma4(acc0,a0.w,b3); \
    fma4(acc1,a1.x,b0); fma4(acc1,a1.y,b1); fma4(acc1,a1.z,b2); fma4(acc1,a1.w,b3); \
  }
template<bool LAST>
__global__ __launch_bounds__(256,4) void k_fused3(const float* __restrict__ Ain,
    const float* __restrict__ W2, const float* __restrict__ B2,
    const float* __restrict__ WL, const float* __restrict__ BL,
    float* __restrict__ Hio, const float* __restrict__ W1n, ushort4* __restrict__ Xout){
  __shared__ float BsA[32*HDIM];  // 16 KB
  __shared__ float BsB[32*HDIM];  // 16 KB
  __shared__ float Ss[FR*HDIM];   // 8 KB, holds t then h'
  int tid = threadIdx.x;
  int m0 = blockIdx.x*FR;
  int tc = tid & 31, tr = tid >> 5;
  int j0 = tc*4;
  int lr0 = tr*2, lr1 = tr*2+1;
  float4 acc0, acc1;
  float* Bcur = BsA;
  float* Bnxt = BsB;

  stage_dma(Bcur, W2, 0, tid);
  __syncthreads();

  // ---- stage A: acc = agg @ W2 ----
  acc0 = make_float4(0,0,0,0); acc1 = acc0;
  {
    const float* A0 = Ain + (size_t)(m0 + lr0)*HDIM;
    const float* A1 = Ain + (size_t)(m0 + lr1)*HDIM;
    for (int kc=0; kc<HDIM; kc+=32){
      if (kc+32 < HDIM) stage_dma(Bnxt, W2, kc+32, tid);
      else              stage_dma(Bnxt, WL, 0, tid);
      FMA_BLOCK(Bcur, A0 + kc, A1 + kc);
      __syncthreads();
      float* tmp = Bcur; Bcur = Bnxt; Bnxt = tmp;
    }
  }
  {
    float4 b2v = *(const float4*)(B2 + j0);
    float4 v;
    v.x=ssp_f(acc0.x+b2v.x); v.y=ssp_f(acc0.y+b2v.y); v.z=ssp_f(acc0.z+b2v.z); v.w=ssp_f(acc0.w+b2v.w);
    *(float4*)(Ss + lr0*HDIM + j0) = v;
    v.x=ssp_f(acc1.x+b2v.x); v.y=ssp_f(acc1.y+b2v.y); v.z=ssp_f(acc1.z+b2v.z); v.w=ssp_f(acc1.w+b2v.w);
    *(float4*)(Ss + lr1*HDIM + j0) = v;
  }
  __syncthreads();

  // ---- stage B: acc = t @ WL ; h' = h + acc + bl ----
  acc0 = make_float4(0,0,0,0); acc1 = acc0;
  for (int kc=0; kc<HDIM; kc+=32){
    if (kc+32 < HDIM)   stage_dma(Bnxt, WL, kc+32, tid);
    else if (!LAST)     stage_dma(Bnxt, W1n, 0, tid);
    FMA_BLOCK(Bcur, Ss + lr0*HDIM + kc, Ss + lr1*HDIM + kc);
    __syncthreads();
    float* tmp = Bcur; Bcur = Bnxt; Bnxt = tmp;
  }
  {
    float4 blv = *(const float4*)(BL + j0);
    float* H0 = Hio + (size_t)(m0 + lr0)*HDIM + j0;
    float* H1 = Hio + (size_t)(m0 + lr1)*HDIM + j0;
    float4 hv;
    hv = *(float4*)H0;
    hv.x += acc0.x+blv.x; hv.y += acc0.y+blv.y; hv.z += acc0.z+blv.z; hv.w += acc0.w+blv.w;
    *(float4*)H0 = hv; if (!LAST) *(float4*)(Ss + lr0*HDIM + j0) = hv;
    hv = *(float4*)H1;
    hv.x += acc1.x+blv.x; hv.y += acc1.y+blv.y; hv.z += acc1.z+blv.z; hv.w += acc1.w+blv.w;
    *(float4*)H1 = hv; if (!LAST) *(float4*)(Ss + lr1*HDIM + j0) = hv;
  }
  if (LAST) return;
  __syncthreads();

  // ---- stage C: xh_next(bf16) = h' @ W1n ----
  acc0 = make_float4(0,0,0,0); acc1 = acc0;
  for (int kc=0; kc<HDIM; kc+=32){
    if (kc+32 < HDIM) stage_dma(Bnxt, W1n, kc+32, tid);
    FMA_BLOCK(Bcur, Ss + lr0*HDIM + kc, Ss + lr1*HDIM + kc);
    __syncthreads();
    float* tmp = Bcur; Bcur = Bnxt; Bnxt = tmp;
  }
  ushort4 o;
  o.x=f2bf(acc0.x); o.y=f2bf(acc0.y); o.z=f2bf(acc0.z); o.w=f2bf(acc0.w);
  Xout[(size_t)(m0 + lr0)*32 + tc] = o;
  o.x=f2bf(acc1.x); o.y=f2bf(acc1.y); o.z=f2bf(acc1.z); o.w=f2bf(acc1.w);
  Xout[(size_t)(m0 + lr1)*32 + tc] = o;
}

// ---------------- output MLP: per-node scalar (no atomics) ----------------
__global__ __launch_bounds__(256) void k_outA(const float* __restrict__ h, const float* __restrict__ w1,
    const float* __restrict__ b1, const float* __restrict__ w2, const float* __restrict__ b2,
    float* __restrict__ nodeval){
  int node = blockIdx.x*4 + (threadIdx.x >> 6);
  int lane = threadIdx.x & 63;
  float acc = b1[lane];
  const float* hrow = h + (size_t)node*HDIM;
  #pragma unroll 4
  for (int k=0;k<HDIM;++k) acc = fmaf(hrow[k], w1[k*64 + lane], acc);
  float s = ssp_f(acc) * w2[lane];
  for (int off=32; off>0; off>>=1) s += __shfl_down(s, off, 64);
  if (lane == 0) nodeval[node] = s + b2[0];
}

// ---------------- graph readout ----------------
__global__ __launch_bounds__(256) void k_outB(const float* __restrict__ nodeval,
    const int* __restrict__ batch, float* __restrict__ out){
  __shared__ float sred[4];
  int g = blockIdx.x;
  int t = threadIdx.x;
  float s = 0.f;
  for (int n = t; n < N_NODES; n += 256)
    if (batch[n] == g) s += nodeval[n];
  for (int off=32; off>0; off>>=1) s += __shfl_down(s, off, 64);
  if ((t & 63) == 0) sred[t >> 6] = s;
  __syncthreads();
  if (t == 0){
    float tot = sred[0] + sred[1] + sred[2] + sred[3];
    out[g] = 1.0f/(1.0f + __expf(-tot));
  }
}

// ---------------- host ----------------
extern "C" void kernel_launch(void* const* d_in, const int* in_sizes, int n_in,
                              void* d_out, int out_size, void* d_ws, size_t ws_size,
                              hipStream_t stream){
  (void)in_sizes; (void)n_in; (void)out_size;
  const int*   z      = (const int*)  d_in[0];
  const float* pos    = (const float*)d_in[1];
  const int*   ei     = (const int*)  d_in[2];
  const int*   batch  = (const int*)  d_in[3];
  const float* emb    = (const float*)d_in[4];
  const float* mlp_w1 = (const float*)d_in[5];
  const float* mlp_b1 = (const float*)d_in[6];
  const float* mlp_w2 = (const float*)d_in[7];
  const float* mlp_b2 = (const float*)d_in[8];
  const float* cf_w1  = (const float*)d_in[9];
  const float* cf_w2  = (const float*)d_in[10];
  const float* cf_b2  = (const float*)d_in[11];
  const float* lin_w  = (const float*)d_in[12];
  const float* lin_b  = (const float*)d_in[13];
  const float* ow1    = (const float*)d_in[14];
  const float* ob1    = (const float*)d_in[15];
  const float* ow2    = (const float*)d_in[16];
  const float* ob2    = (const float*)d_in[17];

  char* wp = (char*)d_ws;
  size_t used = 0;
  auto alloc = [&](size_t bytes)->char*{
    char* p = wp + used;
    used += (bytes + 1023) & ~(size_t)1023;
    return p;
  };
  float*   tab     = (float*)alloc((size_t)NLAYER*TROWS*HDIM*4);
  ushort4* tabp    = (ushort4*)alloc((size_t)NLAYER*1024*64*8);
  float*   h       = (float*)alloc((size_t)N_NODES*HDIM*4);
  ushort4* xhb     = (ushort4*)alloc((size_t)N_NODES*32*8);
  float*   agg     = (float*)alloc((size_t)N_NODES*HDIM*4);
  int*     rowptr  = (int*)  alloc((size_t)(N_NODES+1)*4);
  int*     cursor  = (int*)  alloc((size_t)N_NODES*4);
  int*     srcl    = (int*)  alloc((size_t)N_EDGES*4);
  float*   tl      = (float*)alloc((size_t)N_EDGES*4);
  float*   nodeval = (float*)alloc((size_t)N_NODES*4);
  if (used > ws_size) return;

  hipMemsetAsync(cursor, 0, (size_t)N_NODES*4, stream);

  k_init_h<<<N_NODES*32/256, 256, 0, stream>>>(z, emb, h);
  k_tab   <<<NLAYER*TAB_NB, 256, 0, stream>>>(mlp_w1, mlp_b1, mlp_w2, mlp_b2, tab);
  k_pack  <<<NLAYER*1024*64/256, 256, 0, stream>>>(tab, tabp);
  k_hist  <<<N_EDGES/256, 256, 0, stream>>>(ei, cursor);
  k_scan  <<<1, 1024, 0, stream>>>(cursor, rowptr);
  k_fill  <<<N_EDGES/256, 256, 0, stream>>>(ei, pos, cursor, srcl, tl);

  k_gemm_xh<<<N_NODES/FR, 256, 0, stream>>>(h, cf_w1, xhb);
  for (int l=0; l<NLAYER; ++l){
    k_agg<<<N_NODES/4, 256, 0, stream>>>(rowptr, srcl, tl,
                 tabp + (size_t)l*1024*64, (const ushort2*)xhb, agg);
    if (l < NLAYER-1){
      k_fused3<false><<<N_NODES/FR, 256, 0, stream>>>(agg,
                 cf_w2 + (size_t)l*HDIM*HDIM, cf_b2 + (size_t)l*HDIM,
                 lin_w + (size_t)l*HDIM*HDIM, lin_b + (size_t)l*HDIM, h,
                 cf_w1 + (size_t)(l+1)*HDIM*HDIM, xhb);
    } else {
      k_fused3<true><<<N_NODES/FR, 256, 0, stream>>>(agg,
                 cf_w2 + (size_t)l*HDIM*HDIM, cf_b2 + (size_t)l*HDIM,
                 lin_w + (size_t)l*HDIM*HDIM, lin_b + (size_t)l*HDIM, h,
                 nullptr, nullptr);
    }
  }
  k_outA  <<<N_NODES/4, 256, 0, stream>>>(h, ow1, ob1, ow2, ob2, nodeval);
  k_outB  <<<NGRAPH, 256, 0, stream>>>(nodeval, batch, (float*)d_out);
}